// Round 1
// baseline (486.560 us; speedup 1.0000x reference)
//
#include <hip/hip_runtime.h>

typedef float f32x4 __attribute__((ext_vector_type(4)));
typedef short s16x8 __attribute__((ext_vector_type(8)));

#define DEVI __device__ __forceinline__

DEVI unsigned short f2bf(float f) {
    unsigned int u = __builtin_bit_cast(unsigned int, f);
    u += 0x7fffu + ((u >> 16) & 1u);
    return (unsigned short)(u >> 16);
}

// Geometry: B=4, C=128, H=W=360, r=9, h=w=40, T=1600 tokens, R2=81 features.
// token t = hh*40+ww, feature k = ch*9+cw, pixel (ch*40+hh, cw*40+ww).

// ---------------------------------------------------------------------------
// Kernel 1: 1x1 conv (channel-mix GEMM, MFMA bf16) + rearrange + bf16 store.
// x:[4][128][360][360] f32, Wcv:[128][128], bcv:[128]
// XR: bf16 [bo=512][81][1600]
// Block tile: all 128 out-ch x 160 pixels (4 hh-rows x 40 ww in one (ch,cw)).
__global__ __launch_bounds__(256) void k_conv(
    const float* __restrict__ x, const float* __restrict__ Wcv,
    const float* __restrict__ bcv, unsigned short* __restrict__ XR)
{
    __shared__ __align__(16) unsigned short As[128 * 136]; // Wconv [o][ci]
    __shared__ __align__(16) unsigned short Xs[160 * 136]; // x tile [n][ci]
    const int tid = threadIdx.x;
    int bid = blockIdx.x;
    const int rb = bid % 10; bid /= 10;
    const int cw = bid % 9;  bid /= 9;
    const int ch = bid % 9;  const int b = bid / 9;
    const int H0 = ch * 40 + rb * 4, w0 = cw * 40;
    const int kfeat = ch * 9 + cw;
    const int t0 = rb * 160;

    for (int i = tid; i < 128 * 32; i += 256) {
        const int o = i >> 5, c4 = (i & 31) << 2;
        const float4 v = *reinterpret_cast<const float4*>(Wcv + o * 128 + c4);
        ushort4 hv = { f2bf(v.x), f2bf(v.y), f2bf(v.z), f2bf(v.w) };
        *reinterpret_cast<ushort4*>(&As[o * 136 + c4]) = hv;
    }
    const float* xb = x + (size_t)b * 128 * 129600;
    for (int i = tid; i < 32 * 160; i += 256) {
        const int c4 = (i / 160) << 2, n = i % 160;
        const int r = n / 40, ww = n % 40;
        const float* px = xb + (size_t)(H0 + r) * 360 + w0 + ww;
        ushort4 hv = { f2bf(px[(size_t)(c4 + 0) * 129600]),
                       f2bf(px[(size_t)(c4 + 1) * 129600]),
                       f2bf(px[(size_t)(c4 + 2) * 129600]),
                       f2bf(px[(size_t)(c4 + 3) * 129600]) };
        *reinterpret_cast<ushort4*>(&Xs[n * 136 + c4]) = hv;
    }
    __syncthreads();

    const int lane = tid & 63, wid = tid >> 6;
    const int wm = wid >> 1, wn = wid & 1;
    const int lr = lane & 15, lg = lane >> 4;

    f32x4 acc[4][5] = {};
#pragma unroll
    for (int kk = 0; kk < 4; ++kk) {
        const int koff = kk * 32 + lg * 8;
        s16x8 af[4], bfr[5];
#pragma unroll
        for (int mt = 0; mt < 4; ++mt)
            af[mt] = *reinterpret_cast<const s16x8*>(&As[(wm * 64 + mt * 16 + lr) * 136 + koff]);
#pragma unroll
        for (int nt = 0; nt < 5; ++nt)
            bfr[nt] = *reinterpret_cast<const s16x8*>(&Xs[(wn * 80 + nt * 16 + lr) * 136 + koff]);
#pragma unroll
        for (int mt = 0; mt < 4; ++mt)
#pragma unroll
            for (int nt = 0; nt < 5; ++nt)
                acc[mt][nt] = __builtin_amdgcn_mfma_f32_16x16x32_bf16(af[mt], bfr[nt], acc[mt][nt], 0, 0, 0);
    }
#pragma unroll
    for (int mt = 0; mt < 4; ++mt) {
        const int o0 = wm * 64 + mt * 16 + lg * 4;
        const float4 b4 = *reinterpret_cast<const float4*>(bcv + o0);
        const float badd[4] = { b4.x, b4.y, b4.z, b4.w };
#pragma unroll
        for (int rg = 0; rg < 4; ++rg) {
            const int o = o0 + rg;
            unsigned short* dst = XR + (size_t)(b * 128 + o) * 129600 + (size_t)kfeat * 1600 + t0;
#pragma unroll
            for (int nt = 0; nt < 5; ++nt) {
                const int n = wn * 80 + nt * 16 + lr;
                dst[n] = f2bf(acc[mt][nt][rg] + badd[rg]);
            }
        }
    }
}

// ---------------------------------------------------------------------------
// Kernel 2: per (b,o) Gram G = R R^T (96-padded), row 81 = ones so col 81 = s.
// XR bf16 [512][81][1600] -> G f32 [512][96][96]
__global__ __launch_bounds__(256) void k_gram(
    const unsigned short* __restrict__ XR, float* __restrict__ G)
{
    __shared__ __align__(16) unsigned short Rs[96 * 168];
    const int tid = threadIdx.x;
    const int bo = blockIdx.x;
    for (int i = 81 * 168 + tid; i < 96 * 168; i += 256)
        Rs[i] = (i < 82 * 168) ? (unsigned short)0x3F80 : (unsigned short)0;
    const unsigned short* Rg = XR + (size_t)bo * 129600;
    const int lane = tid & 63, wid = tid >> 6;
    const int wm = wid >> 1, wn = wid & 1;
    const int lr = lane & 15, lg = lane >> 4;
    f32x4 acc[3][3] = {};
    for (int it = 0; it < 10; ++it) {
        const int t0 = it * 160;
        __syncthreads();
        for (int i = tid; i < 81 * 20; i += 256) {
            const int r = i / 20, g = i % 20;
            *reinterpret_cast<s16x8*>(&Rs[r * 168 + g * 8]) =
                *reinterpret_cast<const s16x8*>(Rg + (size_t)r * 1600 + t0 + g * 8);
        }
        __syncthreads();
#pragma unroll
        for (int kk = 0; kk < 5; ++kk) {
            const int koff = kk * 32 + lg * 8;
            s16x8 af[3], bfr[3];
#pragma unroll
            for (int mt = 0; mt < 3; ++mt)
                af[mt] = *reinterpret_cast<const s16x8*>(&Rs[(wm * 48 + mt * 16 + lr) * 168 + koff]);
#pragma unroll
            for (int nt = 0; nt < 3; ++nt)
                bfr[nt] = *reinterpret_cast<const s16x8*>(&Rs[(wn * 48 + nt * 16 + lr) * 168 + koff]);
#pragma unroll
            for (int mt = 0; mt < 3; ++mt)
#pragma unroll
                for (int nt = 0; nt < 3; ++nt)
                    acc[mt][nt] = __builtin_amdgcn_mfma_f32_16x16x32_bf16(af[mt], bfr[nt], acc[mt][nt], 0, 0, 0);
        }
    }
    float* Gb = G + (size_t)bo * 9216;
#pragma unroll
    for (int mt = 0; mt < 3; ++mt)
#pragma unroll
        for (int nt = 0; nt < 3; ++nt)
#pragma unroll
            for (int rg = 0; rg < 4; ++rg) {
                const int row = wm * 48 + mt * 16 + lg * 4 + rg;
                const int col = wn * 48 + nt * 16 + lr;
                Gb[row * 96 + col] = acc[mt][nt][rg];
            }
}

// ---------------------------------------------------------------------------
// Kernel 3: per (b,o) small algebra (f32).
// P = G Wc^T; M = Wb P + u bc^T + bb v^T + 1600 bb bc^T; N = Wa^T M / 9; m = ba^T M / 9
// NT bf16 [bo][q=96][k=96]: NT[q][k<81] = N[k][q], NT[q][81] = m[q], rest 0.
__global__ __launch_bounds__(256) void k_small(
    const float* __restrict__ G, const float* __restrict__ Wa, const float* __restrict__ ba,
    const float* __restrict__ Wb, const float* __restrict__ bb,
    const float* __restrict__ Wc, const float* __restrict__ bc,
    unsigned short* __restrict__ NT)
{
    __shared__ float Gs[82 * 82];
    __shared__ float Ws[81 * 82];
    __shared__ float Pb[81 * 82];
    __shared__ float sv[81];
    __shared__ float su[81];
    __shared__ float mq[81];
    const int tid = threadIdx.x;
    const int bo = blockIdx.x;
    const float* Gg = G + (size_t)bo * 9216;
    for (int i = tid; i < 82 * 82; i += 256) {
        const int r = i / 82, c = i % 82;
        Gs[i] = Gg[r * 96 + c];
    }
    for (int i = tid; i < 81 * 81; i += 256) {
        const int r = i / 81, c = i % 81;
        Ws[r * 82 + c] = Wc[i];
    }
    __syncthreads();
    if (tid < 81) { // v = Wc s  (s[l] = Gs[l][81])
        float a = 0.f;
        for (int l = 0; l < 81; ++l) a += Ws[tid * 82 + l] * Gs[l * 82 + 81];
        sv[tid] = a;
    }
    for (int i = tid; i < 81 * 81; i += 256) { // P[k][q] = sum_l G[k][l] Wc[q][l]
        const int k = i / 81, q = i % 81;
        float a = 0.f;
        for (int l = 0; l < 81; ++l) a += Gs[k * 82 + l] * Ws[q * 82 + l];
        Pb[k * 82 + q] = a;
    }
    __syncthreads();
    for (int i = tid; i < 81 * 81; i += 256) {
        const int r = i / 81, c = i % 81;
        Ws[r * 82 + c] = Wb[i];
    }
    __syncthreads();
    if (tid < 81) { // u = Wb s
        float a = 0.f;
        for (int k = 0; k < 81; ++k) a += Ws[tid * 82 + k] * Gs[k * 82 + 81];
        su[tid] = a;
    }
    __syncthreads();
    for (int i = tid; i < 81 * 81; i += 256) { // M -> Gs[p][q] (col 81 untouched)
        const int p = i / 81, q = i % 81;
        float a = su[p] * bc[q] + bb[p] * (sv[q] + 1600.f * bc[q]);
        for (int k = 0; k < 81; ++k) a += Ws[p * 82 + k] * Pb[k * 82 + q];
        Gs[p * 82 + q] = a;
    }
    __syncthreads();
    for (int i = tid; i < 81 * 81; i += 256) {
        const int r = i / 81, c = i % 81;
        Ws[r * 82 + c] = Wa[i];
    }
    if (tid < 81) { // m[q] = sum_p ba[p] M[p][q] / 9
        float a = 0.f;
        for (int p = 0; p < 81; ++p) a += ba[p] * Gs[p * 82 + tid];
        mq[tid] = a * (1.f / 9.f);
    }
    __syncthreads();
    unsigned short* NTb = NT + (size_t)bo * 9216;
    for (int i = tid; i < 96 * 96; i += 256) {
        const int q = i / 96, k = i % 96;
        float val = 0.f;
        if (q < 81) {
            if (k < 81) {
                float a = 0.f;
                for (int p = 0; p < 81; ++p) a += Ws[p * 82 + k] * Gs[p * 82 + q];
                val = a * (1.f / 9.f);
            } else if (k == 81) {
                val = mq[q];
            }
        }
        NTb[i] = f2bf(val);
    }
}

// ---------------------------------------------------------------------------
// Kernel 4: y[t][q] = sum_k x~[t][k] N[k][q] + m[q], MFMA with D[q][t];
// A = NT rows (preloaded), B = x~ chunk gathered from LDS (ones-row adds m).
// Inverse rearrange on f32 store.
__global__ __launch_bounds__(256) void k_apply(
    const unsigned short* __restrict__ XR, const unsigned short* __restrict__ NT,
    float* __restrict__ out)
{
    __shared__ __align__(16) unsigned short Xs[96 * 168];
    const int tid = threadIdx.x;
    const int bid = blockIdx.x;
    const int half = bid & 1, bo = bid >> 1;
    for (int i = 81 * 168 + tid; i < 96 * 168; i += 256)
        Xs[i] = (i < 82 * 168) ? (unsigned short)0x3F80 : (unsigned short)0;
    const int lane = tid & 63, wid = tid >> 6;
    const int wm = wid >> 1, wn = wid & 1;
    const int lr = lane & 15, lg = lane >> 4;

    const unsigned short* NTb = NT + (size_t)bo * 9216;
    s16x8 af[3][3];
#pragma unroll
    for (int mt = 0; mt < 3; ++mt)
#pragma unroll
        for (int kk = 0; kk < 3; ++kk)
            af[mt][kk] = *reinterpret_cast<const s16x8*>(
                NTb + (wm * 48 + mt * 16 + lr) * 96 + kk * 32 + lg * 8);

    const unsigned short* Rg = XR + (size_t)bo * 129600;
    float* ob = out + (size_t)bo * 129600;

    for (int it = 0; it < 5; ++it) {
        const int t0 = half * 800 + it * 160;
        __syncthreads();
        for (int i = tid; i < 81 * 20; i += 256) {
            const int r = i / 20, g = i % 20;
            *reinterpret_cast<s16x8*>(&Xs[r * 168 + g * 8]) =
                *reinterpret_cast<const s16x8*>(Rg + (size_t)r * 1600 + t0 + g * 8);
        }
        __syncthreads();
        f32x4 acc[3][5] = {};
#pragma unroll
        for (int nt = 0; nt < 5; ++nt) {
            const int tcol = wn * 80 + nt * 16 + lr;
#pragma unroll
            for (int kk = 0; kk < 3; ++kk) {
                const int kbase = kk * 32 + lg * 8;
                s16x8 bfr;
#pragma unroll
                for (int e = 0; e < 8; ++e)
                    bfr[e] = (short)Xs[(kbase + e) * 168 + tcol];
#pragma unroll
                for (int mt = 0; mt < 3; ++mt)
                    acc[mt][nt] = __builtin_amdgcn_mfma_f32_16x16x32_bf16(af[mt][kk], bfr, acc[mt][nt], 0, 0, 0);
            }
        }
#pragma unroll
        for (int mt = 0; mt < 3; ++mt) {
            const int q0 = wm * 48 + mt * 16 + lg * 4;
#pragma unroll
            for (int rg = 0; rg < 4; ++rg) {
                const int q = q0 + rg;
                if (q < 81) {
                    const int chq = q / 9, cwq = q % 9;
#pragma unroll
                    for (int nt = 0; nt < 5; ++nt) {
                        const int t = t0 + wn * 80 + nt * 16 + lr;
                        const int hh = t / 40, ww = t % 40;
                        ob[(chq * 40 + hh) * 360 + cwq * 40 + ww] = acc[mt][nt][rg];
                    }
                }
            }
        }
    }
}

// ---------------------------------------------------------------------------
extern "C" void kernel_launch(void* const* d_in, const int* in_sizes, int n_in,
                              void* d_out, int out_size, void* d_ws, size_t ws_size,
                              hipStream_t stream)
{
    (void)in_sizes; (void)n_in; (void)out_size; (void)ws_size;
    const float* x   = (const float*)d_in[0];
    const float* Wcv = (const float*)d_in[1];
    const float* bcv = (const float*)d_in[2];
    const float* Wa  = (const float*)d_in[3];
    const float* ba  = (const float*)d_in[4];
    const float* Wb  = (const float*)d_in[5];
    const float* bbv = (const float*)d_in[6];
    const float* Wc  = (const float*)d_in[7];
    const float* bc2 = (const float*)d_in[8];
    float* out = (float*)d_out;

    // ws layout: XR bf16 132,710,400 B | G f32 18,874,368 B | NT bf16 9,437,184 B
    unsigned short* XR = (unsigned short*)d_ws;
    float* G = (float*)((char*)d_ws + 132710400ull);
    unsigned short* NT = (unsigned short*)((char*)d_ws + 132710400ull + 18874368ull);

    k_conv <<<3240, 256, 0, stream>>>(x, Wcv, bcv, XR);
    k_gram <<<512,  256, 0, stream>>>(XR, G);
    k_small<<<512,  256, 0, stream>>>(G, Wa, ba, Wb, bbv, Wc, bc2, NT);
    k_apply<<<1024, 256, 0, stream>>>(XR, NT, out);
}

// Round 2
// 436.043 us; speedup vs baseline: 1.1159x; 1.1159x over previous
//
#include <hip/hip_runtime.h>

typedef float f32x4 __attribute__((ext_vector_type(4)));
typedef short s16x8 __attribute__((ext_vector_type(8)));

#define DEVI __device__ __forceinline__

DEVI unsigned short f2bf(float f) {
    unsigned int u = __builtin_bit_cast(unsigned int, f);
    u += 0x7fffu + ((u >> 16) & 1u);
    return (unsigned short)(u >> 16);
}

// Geometry: B=4, C=128, H=W=360, r=9, h=w=40, T=1600 tokens, R2=81 features.
// token t = hh*40+ww, feature k = ch*9+cw, pixel (ch*40+hh, cw*40+ww).

// ---------------------------------------------------------------------------
// Kernel 0: convert Wconv f32[128][128] -> bf16 (L2-resident A operand).
__global__ __launch_bounds__(256) void k_wprep(
    const float* __restrict__ W, unsigned short* __restrict__ Wbf)
{
    const int i = blockIdx.x * 256 + threadIdx.x; // grid 64*256 = 16384
    Wbf[i] = f2bf(W[i]);
}

// ---------------------------------------------------------------------------
// Kernel 1: 1x1 conv (channel-mix GEMM, MFMA bf16) + rearrange + bf16 store.
// x:[4][128][360][360] f32, Wbf:[128][128] bf16, bcv:[128]
// XR: bf16 [bo=512][81][1600]
// Block tile: 128 out-ch x 160 pixels (4 hh-rows x 40 ww in one (ch,cw)).
// A-frags come straight from global (L2); only x is staged in LDS.
__global__ __launch_bounds__(256, 3) void k_conv(
    const float* __restrict__ x, const unsigned short* __restrict__ Wbf,
    const float* __restrict__ bcv, unsigned short* __restrict__ XR)
{
    __shared__ __align__(16) unsigned short Xs[160 * 136]; // x tile [n][ci], 43.5 KB
    const int tid = threadIdx.x;
    int bid = blockIdx.x;
    const int rb = bid % 10; bid /= 10;
    const int cw = bid % 9;  bid /= 9;
    const int ch = bid % 9;  const int b = bid / 9;
    const int H0 = ch * 40 + rb * 4, w0 = cw * 40;
    const int kfeat = ch * 9 + cw;
    const int t0 = rb * 160;

    // Stage x: 20 float4 loads/thread (contiguous 160B row segments).
    const float* xb = x + (size_t)b * 128 * 129600;
    for (int i = tid; i < 5120; i += 256) {
        const int g = i % 40, c = i / 40;
        const int hh = g / 10, ww0 = (g % 10) * 4;
        const float4 v = *reinterpret_cast<const float4*>(
            xb + (size_t)c * 129600 + (size_t)(H0 + hh) * 360 + w0 + ww0);
        const int n0 = hh * 40 + ww0;
        Xs[(n0 + 0) * 136 + c] = f2bf(v.x);
        Xs[(n0 + 1) * 136 + c] = f2bf(v.y);
        Xs[(n0 + 2) * 136 + c] = f2bf(v.z);
        Xs[(n0 + 3) * 136 + c] = f2bf(v.w);
    }
    __syncthreads();

    const int lane = tid & 63, wid = tid >> 6;
    const int wm = wid >> 1, wn = wid & 1;
    const int lr = lane & 15, lg = lane >> 4;

    f32x4 acc[4][5] = {};
#pragma unroll
    for (int kk = 0; kk < 4; ++kk) {
        const int koff = kk * 32 + lg * 8;
        s16x8 af[4], bfr[5];
#pragma unroll
        for (int mt = 0; mt < 4; ++mt)
            af[mt] = *reinterpret_cast<const s16x8*>(
                Wbf + (wm * 64 + mt * 16 + lr) * 128 + koff);
#pragma unroll
        for (int nt = 0; nt < 5; ++nt)
            bfr[nt] = *reinterpret_cast<const s16x8*>(&Xs[(wn * 80 + nt * 16 + lr) * 136 + koff]);
#pragma unroll
        for (int mt = 0; mt < 4; ++mt)
#pragma unroll
            for (int nt = 0; nt < 5; ++nt)
                acc[mt][nt] = __builtin_amdgcn_mfma_f32_16x16x32_bf16(af[mt], bfr[nt], acc[mt][nt], 0, 0, 0);
    }
#pragma unroll
    for (int mt = 0; mt < 4; ++mt) {
        const int o0 = wm * 64 + mt * 16 + lg * 4;
        const float4 b4 = *reinterpret_cast<const float4*>(bcv + o0);
        const float badd[4] = { b4.x, b4.y, b4.z, b4.w };
#pragma unroll
        for (int rg = 0; rg < 4; ++rg) {
            const int o = o0 + rg;
            unsigned short* dst = XR + (size_t)(b * 128 + o) * 129600 + (size_t)kfeat * 1600 + t0;
#pragma unroll
            for (int nt = 0; nt < 5; ++nt) {
                const int n = wn * 80 + nt * 16 + lr;
                dst[n] = f2bf(acc[mt][nt][rg] + badd[rg]);
            }
        }
    }
}

// ---------------------------------------------------------------------------
// Kernel 2: per (b,o) Gram G = R R^T (96-padded), row 81 = ones so col 81 = s.
// XR bf16 [512][81][1600] -> G f32 [512][96][96]
__global__ __launch_bounds__(256) void k_gram(
    const unsigned short* __restrict__ XR, float* __restrict__ G)
{
    __shared__ __align__(16) unsigned short Rs[96 * 168];
    const int tid = threadIdx.x;
    const int bo = blockIdx.x;
    for (int i = 81 * 168 + tid; i < 96 * 168; i += 256)
        Rs[i] = (i < 82 * 168) ? (unsigned short)0x3F80 : (unsigned short)0;
    const unsigned short* Rg = XR + (size_t)bo * 129600;
    const int lane = tid & 63, wid = tid >> 6;
    const int wm = wid >> 1, wn = wid & 1;
    const int lr = lane & 15, lg = lane >> 4;
    f32x4 acc[3][3] = {};
    for (int it = 0; it < 10; ++it) {
        const int t0 = it * 160;
        __syncthreads();
        for (int i = tid; i < 81 * 20; i += 256) {
            const int r = i / 20, g = i % 20;
            *reinterpret_cast<s16x8*>(&Rs[r * 168 + g * 8]) =
                *reinterpret_cast<const s16x8*>(Rg + (size_t)r * 1600 + t0 + g * 8);
        }
        __syncthreads();
#pragma unroll
        for (int kk = 0; kk < 5; ++kk) {
            const int koff = kk * 32 + lg * 8;
            s16x8 af[3], bfr[3];
#pragma unroll
            for (int mt = 0; mt < 3; ++mt)
                af[mt] = *reinterpret_cast<const s16x8*>(&Rs[(wm * 48 + mt * 16 + lr) * 168 + koff]);
#pragma unroll
            for (int nt = 0; nt < 3; ++nt)
                bfr[nt] = *reinterpret_cast<const s16x8*>(&Rs[(wn * 48 + nt * 16 + lr) * 168 + koff]);
#pragma unroll
            for (int mt = 0; mt < 3; ++mt)
#pragma unroll
                for (int nt = 0; nt < 3; ++nt)
                    acc[mt][nt] = __builtin_amdgcn_mfma_f32_16x16x32_bf16(af[mt], bfr[nt], acc[mt][nt], 0, 0, 0);
        }
    }
    float* Gb = G + (size_t)bo * 9216;
#pragma unroll
    for (int mt = 0; mt < 3; ++mt)
#pragma unroll
        for (int nt = 0; nt < 3; ++nt)
#pragma unroll
            for (int rg = 0; rg < 4; ++rg) {
                const int row = wm * 48 + mt * 16 + lg * 4 + rg;
                const int col = wn * 48 + nt * 16 + lr;
                Gb[row * 96 + col] = acc[mt][nt][rg];
            }
}

// ---------------------------------------------------------------------------
// Kernel 3: per (b,o) small algebra (f32).
// P = G Wc^T; M = Wb P + u bc^T + bb v^T + 1600 bb bc^T; N = Wa^T M / 9; m = ba^T M / 9
// NT bf16 [bo][q=96][k=96]: NT[q][k<81] = N[k][q], NT[q][81] = m[q], rest 0.
__global__ __launch_bounds__(256) void k_small(
    const float* __restrict__ G, const float* __restrict__ Wa, const float* __restrict__ ba,
    const float* __restrict__ Wb, const float* __restrict__ bb,
    const float* __restrict__ Wc, const float* __restrict__ bc,
    unsigned short* __restrict__ NT)
{
    __shared__ float Gs[82 * 82];
    __shared__ float Ws[81 * 82];
    __shared__ float Pb[81 * 82];
    __shared__ float sv[81];
    __shared__ float su[81];
    __shared__ float mq[81];
    const int tid = threadIdx.x;
    const int bo = blockIdx.x;
    const float* Gg = G + (size_t)bo * 9216;
    for (int i = tid; i < 82 * 82; i += 256) {
        const int r = i / 82, c = i % 82;
        Gs[i] = Gg[r * 96 + c];
    }
    for (int i = tid; i < 81 * 81; i += 256) {
        const int r = i / 81, c = i % 81;
        Ws[r * 82 + c] = Wc[i];
    }
    __syncthreads();
    if (tid < 81) { // v = Wc s  (s[l] = Gs[l][81])
        float a = 0.f;
        for (int l = 0; l < 81; ++l) a += Ws[tid * 82 + l] * Gs[l * 82 + 81];
        sv[tid] = a;
    }
    for (int i = tid; i < 81 * 81; i += 256) { // P[k][q] = sum_l G[k][l] Wc[q][l]
        const int k = i / 81, q = i % 81;
        float a = 0.f;
        for (int l = 0; l < 81; ++l) a += Gs[k * 82 + l] * Ws[q * 82 + l];
        Pb[k * 82 + q] = a;
    }
    __syncthreads();
    for (int i = tid; i < 81 * 81; i += 256) {
        const int r = i / 81, c = i % 81;
        Ws[r * 82 + c] = Wb[i];
    }
    __syncthreads();
    if (tid < 81) { // u = Wb s
        float a = 0.f;
        for (int k = 0; k < 81; ++k) a += Ws[tid * 82 + k] * Gs[k * 82 + 81];
        su[tid] = a;
    }
    __syncthreads();
    for (int i = tid; i < 81 * 81; i += 256) { // M -> Gs[p][q] (col 81 untouched)
        const int p = i / 81, q = i % 81;
        float a = su[p] * bc[q] + bb[p] * (sv[q] + 1600.f * bc[q]);
        for (int k = 0; k < 81; ++k) a += Ws[p * 82 + k] * Pb[k * 82 + q];
        Gs[p * 82 + q] = a;
    }
    __syncthreads();
    for (int i = tid; i < 81 * 81; i += 256) {
        const int r = i / 81, c = i % 81;
        Ws[r * 82 + c] = Wa[i];
    }
    if (tid < 81) { // m[q] = sum_p ba[p] M[p][q] / 9
        float a = 0.f;
        for (int p = 0; p < 81; ++p) a += ba[p] * Gs[p * 82 + tid];
        mq[tid] = a * (1.f / 9.f);
    }
    __syncthreads();
    unsigned short* NTb = NT + (size_t)bo * 9216;
    for (int i = tid; i < 96 * 96; i += 256) {
        const int q = i / 96, k = i % 96;
        float val = 0.f;
        if (q < 81) {
            if (k < 81) {
                float a = 0.f;
                for (int p = 0; p < 81; ++p) a += Ws[p * 82 + k] * Gs[p * 82 + q];
                val = a * (1.f / 9.f);
            } else if (k == 81) {
                val = mq[q];
            }
        }
        NTb[i] = f2bf(val);
    }
}

// ---------------------------------------------------------------------------
// Kernel 4: y[t][q] = sum_k x~[t][k] N[k][q] + m[q], MFMA with D[q][t];
// A = NT rows (preloaded), B = x~ chunk gathered from LDS (ones-row adds m).
// Split 5 ways over t per (b,o) for occupancy. Inverse rearrange on f32 store.
__global__ __launch_bounds__(256) void k_apply(
    const unsigned short* __restrict__ XR, const unsigned short* __restrict__ NT,
    float* __restrict__ out)
{
    __shared__ __align__(16) unsigned short Xs[96 * 168];
    const int tid = threadIdx.x;
    const int bid = blockIdx.x;
    const int fifth = bid % 5, bo = bid / 5;
    for (int i = 81 * 168 + tid; i < 96 * 168; i += 256)
        Xs[i] = (i < 82 * 168) ? (unsigned short)0x3F80 : (unsigned short)0;
    const int lane = tid & 63, wid = tid >> 6;
    const int wm = wid >> 1, wn = wid & 1;
    const int lr = lane & 15, lg = lane >> 4;

    const unsigned short* NTb = NT + (size_t)bo * 9216;
    s16x8 af[3][3];
#pragma unroll
    for (int mt = 0; mt < 3; ++mt)
#pragma unroll
        for (int kk = 0; kk < 3; ++kk)
            af[mt][kk] = *reinterpret_cast<const s16x8*>(
                NTb + (wm * 48 + mt * 16 + lr) * 96 + kk * 32 + lg * 8);

    const unsigned short* Rg = XR + (size_t)bo * 129600;
    float* ob = out + (size_t)bo * 129600;

    for (int it = 0; it < 2; ++it) {
        const int t0 = fifth * 320 + it * 160;
        __syncthreads();
        for (int i = tid; i < 81 * 20; i += 256) {
            const int r = i / 20, g = i % 20;
            *reinterpret_cast<s16x8*>(&Xs[r * 168 + g * 8]) =
                *reinterpret_cast<const s16x8*>(Rg + (size_t)r * 1600 + t0 + g * 8);
        }
        __syncthreads();
        f32x4 acc[3][5] = {};
#pragma unroll
        for (int nt = 0; nt < 5; ++nt) {
            const int tcol = wn * 80 + nt * 16 + lr;
#pragma unroll
            for (int kk = 0; kk < 3; ++kk) {
                const int kbase = kk * 32 + lg * 8;
                s16x8 bfr;
#pragma unroll
                for (int e = 0; e < 8; ++e)
                    bfr[e] = (short)Xs[(kbase + e) * 168 + tcol];
#pragma unroll
                for (int mt = 0; mt < 3; ++mt)
                    acc[mt][nt] = __builtin_amdgcn_mfma_f32_16x16x32_bf16(af[mt][kk], bfr, acc[mt][nt], 0, 0, 0);
            }
        }
#pragma unroll
        for (int mt = 0; mt < 3; ++mt) {
            const int q0 = wm * 48 + mt * 16 + lg * 4;
#pragma unroll
            for (int rg = 0; rg < 4; ++rg) {
                const int q = q0 + rg;
                if (q < 81) {
                    const int chq = q / 9, cwq = q % 9;
#pragma unroll
                    for (int nt = 0; nt < 5; ++nt) {
                        const int t = t0 + wn * 80 + nt * 16 + lr;
                        const int hh = t / 40, ww = t % 40;
                        ob[(chq * 40 + hh) * 360 + cwq * 40 + ww] = acc[mt][nt][rg];
                    }
                }
            }
        }
    }
}

// ---------------------------------------------------------------------------
extern "C" void kernel_launch(void* const* d_in, const int* in_sizes, int n_in,
                              void* d_out, int out_size, void* d_ws, size_t ws_size,
                              hipStream_t stream)
{
    (void)in_sizes; (void)n_in; (void)out_size; (void)ws_size;
    const float* x   = (const float*)d_in[0];
    const float* Wcv = (const float*)d_in[1];
    const float* bcv = (const float*)d_in[2];
    const float* Wa  = (const float*)d_in[3];
    const float* ba  = (const float*)d_in[4];
    const float* Wb  = (const float*)d_in[5];
    const float* bbv = (const float*)d_in[6];
    const float* Wc  = (const float*)d_in[7];
    const float* bc2 = (const float*)d_in[8];
    float* out = (float*)d_out;

    // ws layout: XR bf16 132,710,400 | G f32 18,874,368 | NT bf16 9,437,184 | Wbf 32,768
    unsigned short* XR = (unsigned short*)d_ws;
    float* G = (float*)((char*)d_ws + 132710400ull);
    unsigned short* NT = (unsigned short*)((char*)d_ws + 132710400ull + 18874368ull);
    unsigned short* Wbf = (unsigned short*)((char*)d_ws + 132710400ull + 18874368ull + 9437184ull);

    k_wprep<<<64,   256, 0, stream>>>(Wcv, Wbf);
    k_conv <<<3240, 256, 0, stream>>>(x, Wbf, bcv, XR);
    k_gram <<<512,  256, 0, stream>>>(XR, G);
    k_small<<<512,  256, 0, stream>>>(G, Wa, ba, Wb, bbv, Wc, bc2, NT);
    k_apply<<<2560, 256, 0, stream>>>(XR, NT, out);
}